// Round 7
// baseline (381.882 us; speedup 1.0000x reference)
//
#include <hip/hip_runtime.h>
#include <hip/hip_cooperative_groups.h>

// Problem constants (image 128x128, TILE_SIZE=64)
#define IMG 128
#define TSZ 64
#define NTILES 4          // (128/64)^2
#define PMAX 2048
#define SELCAP 4096       // candidate cap per tile (expected ~2090)
#define NHIST 4096        // linear depth buckets (width 1/256 depth unit)
#define NCHUNK 16
#define CHUNK 128         // PMAX / NCHUNK
#define NPIX 4096         // TSZ*TSZ
#define PLANE ((size_t)NTILES * NCHUNK * NPIX)   // 262144 floats per plane
#define NTHR 256
#define SBLK 64           // select_k grid (coop co-residency trivially satisfied)
#define RUNITS 512        // render units: tile(4) x chunk(16) x pseg(8)
#define FLAGSTRIDE 16     // one cache line per flag
#define NEPOCH 3

typedef unsigned short u16;
typedef unsigned int uint32;
typedef unsigned long long u64;

// Linear depth bucketing: monotone in depth, uniform occupancy for uniform
// depths (float-bits>>20 concentrated ~56 buckets -> atomic serialization).
__device__ __forceinline__ uint32 dbucket(float d) {
    int b = (int)(d * 256.0f);
    return (uint32)min(max(b, 0), NHIST - 1);
}

__device__ __forceinline__ void gauss_rect(const float* means, const float* cov,
                                           int i, float& rminx, float& rminy,
                                           float& rmaxx, float& rmaxy) {
    const float4 cv = ((const float4*)cov)[i];           // a, b, c2, d
    float det = cv.x * cv.w - cv.y * cv.z;
    float mid = 0.5f * (cv.x + cv.w);
    float s = sqrtf(fmaxf(mid * mid - det, 0.1f));
    float radius = 3.0f * ceilf(sqrtf(fmaxf(mid + s, mid - s)));
    const float2 m = ((const float2*)means)[i];
    rminx = fminf(fmaxf(m.x - radius, 0.f), (float)(IMG - 1));
    rmaxx = fminf(fmaxf(m.x + radius, 0.f), (float)(IMG - 1));
    rminy = fminf(fmaxf(m.y - radius, 0.f), (float)(IMG - 1));
    rmaxy = fminf(fmaxf(m.y + radius, 0.f), (float)(IMG - 1));
}

__device__ __forceinline__ bool tile_overlap(int t, float rminx, float rminy,
                                             float rmaxx, float rmaxy) {
    float wmin = (float)((t & 1) * TSZ), hmin = (float)((t >> 1) * TSZ);
    float wmax = wmin + (float)(TSZ - 1), hmax = hmin + (float)(TSZ - 1);
    return (fminf(rmaxx, wmax) > fmaxf(rminx, wmin)) &&
           (fminf(rmaxy, hmax) > fmaxf(rminy, hmin));
}

// Init-free inter-block barrier for SBLK co-resident blocks. Per-epoch,
// per-block flag words (own cache line); "arrived" = magic(epoch) which can
// never equal the 0xAAAAAAAA ws poison, so no zero-init pass is needed.
// ~1 us vs ~55 us for cg::grid_group::sync() at 512 blocks (R6 measurement).
__device__ __forceinline__ void sbar(uint32* flags, int ep, int blk) {
    __syncthreads();
    if (threadIdx.x == 0) {
        __threadfence();                                  // release prior writes
        __hip_atomic_store(&flags[(ep * SBLK + blk) * FLAGSTRIDE],
                           0x51700000u + (uint32)ep,
                           __ATOMIC_RELEASE, __HIP_MEMORY_SCOPE_AGENT);
    }
    if (threadIdx.x < SBLK) {
        const uint32 want = 0x51700000u + (uint32)ep;
        while (__hip_atomic_load(&flags[(ep * SBLK + (int)threadIdx.x) * FLAGSTRIDE],
                                 __ATOMIC_ACQUIRE, __HIP_MEMORY_SCOPE_AGENT) != want)
            __builtin_amdgcn_s_sleep(2);
    }
    __syncthreads();
}

// ============================ phase bodies ==================================

__device__ __forceinline__ void do_tmb(int gtid, int gsize,
        const float* means, const float* cov, const float* depths,
        u16* tmb, int N) {
    for (int i = gtid; i < N; i += gsize) {
        float rminx, rminy, rmaxx, rmaxy;
        gauss_rect(means, cov, i, rminx, rminy, rmaxx, rmaxy);
        uint32 b = dbucket(depths[i]);
        uint32 mask = 0;
        #pragma unroll
        for (int t = 0; t < NTILES; t++)
            if (tile_overlap(t, rminx, rminy, rmaxx, rmaxy)) mask |= (1u << t);
        tmb[i] = (u16)((mask << 12) | b);
    }
}

// tile in [0,4): LDS histogram from tmb, scan -> b*, bucketBase, selCount;
// also zeroes bucketFill and combineCtr (so no standalone zero pass exists).
__device__ __forceinline__ void do_findb_tile(int tile, int tid,
        uint32* hh, uint32* part, uint32* sBM, const u16* tmb, int N,
        uint32* bstar, uint32* selCount, uint32* bucketBase,
        uint32* bucketFill, uint32* combineCtr) {
    if (tid == 0) { sBM[0] = NHIST - 1; sBM[1] = 0; }
    if (tid < 8) combineCtr[tile * 8 + tid] = 0;
    for (int j = tid; j < NHIST; j += NTHR) hh[j] = 0;
    __syncthreads();
    const uint32 bit = 1u << (12 + tile);
    for (int i = tid; i < N; i += NTHR) {
        uint32 tm = tmb[i];
        if (tm & bit) atomicAdd(&hh[tm & 0xFFFu], 1u);    // LDS atomic
    }
    __syncthreads();
    uint32 local = 0;
    #pragma unroll
    for (int b = 0; b < 16; b++) local += hh[tid * 16 + b];
    part[tid] = local;
    __syncthreads();
    for (int off = 1; off < NTHR; off <<= 1) {
        uint32 v = part[tid];
        uint32 u = (tid >= off) ? part[tid - off] : 0u;
        __syncthreads();
        part[tid] = v + u;
        __syncthreads();
    }
    uint32 incl = part[tid], excl = incl - local;
    uint32 run = excl;
    #pragma unroll
    for (int b = 0; b < 16; b++) {
        uint32 j = (uint32)(tid * 16 + b);
        bucketBase[(size_t)tile * NHIST + j] = run;
        bucketFill[(size_t)tile * NHIST + j] = 0u;
        run += hh[j];
    }
    if (excl < PMAX && incl >= PMAX) {                    // unique crossing thread
        uint32 cum = excl;
        for (int b = 0; b < 16; b++) {
            cum += hh[tid * 16 + b];
            if (cum >= PMAX) { sBM[0] = (uint32)(tid * 16 + b); sBM[1] = cum; break; }
        }
    }
    __syncthreads();
    if (tid == 0) {
        bstar[tile] = sBM[0];
        selCount[tile] = (sBM[1] != 0) ? sBM[1] : part[NTHR - 1];
    }
}

__device__ __forceinline__ void do_compact(int gtid, int gsize,
        const u16* tmb, const float* depths, const uint32* bstar,
        const uint32* bucketBase, uint32* bucketFill, u64* sel, int N) {
    for (int i = gtid; i < N; i += gsize) {
        uint32 tm = tmb[i];
        uint32 mask = tm >> 12;
        if (!mask) continue;
        uint32 b = tm & 0xFFFu;
        u64 key = ((u64)__float_as_uint(depths[i]) << 32) | (uint32)i;
        #pragma unroll
        for (int t = 0; t < NTILES; t++) {
            if (((mask >> t) & 1u) && b <= bstar[t]) {
                uint32 pos = bucketBase[(size_t)t * NHIST + b]
                           + atomicAdd(&bucketFill[(size_t)t * NHIST + b], 1u);
                if (pos < SELCAP) sel[(size_t)t * SELCAP + pos] = key;
            }
        }
    }
}

// unit in [0,64): exact rank = #{j: key_j < key_i} (keys unique) = sorted
// slot; emit render-param record. Slots in [M,PMAX) get explicit zero pads
// (replaces the old params pre-zeroing).
__device__ __forceinline__ void do_rank(int unit, int tid, u64* keys,
        const u64* sel, const uint32* selCount,
        const float* means, const float* cov,
        const float* color, const float* opac, float* params) {
    const int tile = unit >> 4;
    uint32 M = selCount[tile]; if (M > SELCAP) M = SELCAP;
    uint32 Mp = (M + 7u) & ~7u;
    const u64* s = sel + (size_t)tile * SELCAP;
    for (uint32 j = tid; j < Mp; j += NTHR)
        keys[j] = (j < M) ? s[j] : ~0ULL;
    __syncthreads();
    uint32 i = (uint32)(unit & 15) * NTHR + (uint32)tid;
    if (i < M) {
        u64 ki = keys[i];
        uint32 r = 0;
        const ulonglong2* k2 = (const ulonglong2*)keys;
        uint32 n2 = Mp >> 1;
        #pragma unroll 8
        for (uint32 j = 0; j < n2; j++) {
            ulonglong2 kk = k2[j];                        // LDS broadcast (16B)
            r += (kk.x < ki) ? 1u : 0u;
            r += (kk.y < ki) ? 1u : 0u;
        }
        if (r < PMAX) {
            uint32 idx = (uint32)(ki & 0xffffffffu);
            float a = cov[4*idx], b = cov[4*idx+1], c2 = cov[4*idx+2], d = cov[4*idx+3];
            float invdet = 1.0f / fmaxf(a * d - b * c2, 1e-6f);
            float4 p0, p1, p2;
            p0.x = means[2*idx]; p0.y = means[2*idx+1];
            p0.z = d * invdet;                 // c00
            p0.w = -(b + c2) * invdet;         // c01 + c10
            p1.x = a * invdet;                 // c11
            p1.y = opac[idx];
            p1.z = color[3*idx]; p1.w = color[3*idx+1];
            p2.x = color[3*idx+2];
            p2.y = __uint_as_float((uint32)(ki >> 32));   // depth
            p2.z = 0.f; p2.w = 0.f;
            float4* P = (float4*)(params + ((size_t)tile * PMAX + r) * 12);
            P[0] = p0; P[1] = p1; P[2] = p2;
        }
    } else if (i < PMAX) {                                // zero-pad slot i
        float4 z = {0.f, 0.f, 0.f, 0.f};
        float4* P = (float4*)(params + ((size_t)tile * PMAX + i) * 12);
        P[0] = z; P[1] = z; P[2] = z;
    }
}

// unit in [0,512): 2 px/thread (rows y, y+32 share all LDS reads).
__device__ __forceinline__ void do_render(int unit, int tid, float4* gp,
        const float* params, float* partials) {
    const int tile  = unit >> 7;
    const int chunk = (unit >> 3) & 15;
    const int pseg  = unit & 7;
    const float4* src = (const float4*)(params + ((size_t)tile * PMAX + (size_t)chunk * CHUNK) * 12);
    for (int j = tid; j < CHUNK * 3; j += NTHR) gp[j] = src[j];
    __syncthreads();
    const int p0 = pseg * 256 + tid;               // rows pseg*4 .. pseg*4+3
    float px  = (float)((tile & 1) * TSZ + (p0 & 63));
    float py0 = (float)((tile >> 1) * TSZ + (p0 >> 6));
    float py1 = py0 + 32.0f;
    float T0 = 1.f, cr0 = 0.f, cg0 = 0.f, cb0 = 0.f, dp0 = 0.f, ac0 = 0.f;
    float T1 = 1.f, cr1 = 0.f, cg1 = 0.f, cb1 = 0.f, dp1 = 0.f, ac1 = 0.f;
    #pragma unroll 4
    for (int g = 0; g < CHUNK; g++) {
        float4 q0 = gp[3*g], q1 = gp[3*g+1], q2 = gp[3*g+2];
        float dx   = px - q0.x;
        float dx2c = dx * dx * q0.z;
        float dxw  = dx * q0.w;
        float dy, power, al, w;
        dy = py0 - q0.y;
        power = -0.5f * (dx2c + dy * dy * q1.x + dy * dxw);
        al = fminf(__expf(power) * q1.y, 0.99f);
        w = al * T0;
        cr0 += w * q1.z; cg0 += w * q1.w; cb0 += w * q2.x;
        dp0 += w * q2.y; ac0 += w;
        T0 *= (1.f - al);
        dy = py1 - q0.y;
        power = -0.5f * (dx2c + dy * dy * q1.x + dy * dxw);
        al = fminf(__expf(power) * q1.y, 0.99f);
        w = al * T1;
        cr1 += w * q1.z; cg1 += w * q1.w; cb1 += w * q2.x;
        dp1 += w * q2.y; ac1 += w;
        T1 *= (1.f - al);
    }
    size_t base0 = ((size_t)tile * NCHUNK + chunk) * NPIX + (size_t)p0;
    size_t base1 = base0 + 2048;                   // row +32
    partials[0*PLANE + base0] = T0;  partials[0*PLANE + base1] = T1;
    partials[1*PLANE + base0] = cr0; partials[1*PLANE + base1] = cr1;
    partials[2*PLANE + base0] = cg0; partials[2*PLANE + base1] = cg1;
    partials[3*PLANE + base0] = cb0; partials[3*PLANE + base1] = cb1;
    partials[4*PLANE + base0] = dp0; partials[4*PLANE + base1] = dp1;
    partials[5*PLANE + base0] = ac0; partials[5*PLANE + base1] = ac1;
}

// fold chunks for one pixel via (T1*T2, S1 + T1*S2); write final output.
__device__ __forceinline__ void do_combine_px(int tile, int p,
        const float* partials, float* out) {
    float T = 1.f, cr = 0.f, cg = 0.f, cb = 0.f, dep = 0.f, acc = 0.f;
    #pragma unroll
    for (int c = 0; c < NCHUNK; c++) {
        size_t base = ((size_t)tile * NCHUNK + c) * NPIX + (size_t)p;
        float Tk = partials[0*PLANE + base];
        cr  += T * partials[1*PLANE + base];
        cg  += T * partials[2*PLANE + base];
        cb  += T * partials[3*PLANE + base];
        dep += T * partials[4*PLANE + base];
        acc += T * partials[5*PLANE + base];
        T *= Tk;
    }
    int gx = (tile & 1) * TSZ + (p & 63);
    int gy = (tile >> 1) * TSZ + (p >> 6);
    int pix = gy * IMG + gx;
    float wb = 1.f - acc;                           // WHITE_BKGD
    out[3*pix+0] = cr + wb;
    out[3*pix+1] = cg + wb;
    out[3*pix+2] = cb + wb;
    out[IMG*IMG*3 + pix] = dep;
    out[IMG*IMG*4 + pix] = acc;
}

// ============================ kernel 1: select ==============================
// Cooperative (co-residency guarantee only; grid.sync replaced by sbar).
__global__ __launch_bounds__(NTHR, 2) void select_k(
        const float* __restrict__ means, const float* __restrict__ cov,
        const float* __restrict__ color, const float* __restrict__ opac,
        const float* __restrict__ depths, int N,
        u16* __restrict__ tmb, uint32* __restrict__ bstar,
        uint32* __restrict__ selCount, uint32* __restrict__ bucketBase,
        uint32* __restrict__ bucketFill, u64* __restrict__ sel,
        float* __restrict__ params, uint32* __restrict__ combineCtr,
        uint32* __restrict__ flags) {
    const int blk = blockIdx.x, tid = threadIdx.x;
    const int gtid = blk * NTHR + tid, gsize = gridDim.x * NTHR;
    __shared__ __align__(16) char shraw[SELCAP * 8];   // 32 KB, phase-aliased
    __shared__ uint32 part[NTHR];
    __shared__ uint32 sBM[2];

    do_tmb(gtid, gsize, means, cov, depths, tmb, N);
    sbar(flags, 0, blk);
    if (blk < NTILES)
        do_findb_tile(blk, tid, (uint32*)shraw, part, sBM, tmb, N,
                      bstar, selCount, bucketBase, bucketFill, combineCtr);
    sbar(flags, 1, blk);
    do_compact(gtid, gsize, tmb, depths, bstar, bucketBase, bucketFill, sel, N);
    sbar(flags, 2, blk);
    do_rank(blk, tid, (u64*)shraw, sel, selCount, means, cov, color, opac, params);
}

// ============================ kernel 2: render+combine ======================
// Plain launch, 512 blocks. Last-arriver block per (tile,pseg) folds the 16
// chunk partials (device-scope fetch_add + threadfence; deadlock-free
// regardless of scheduling; agent-scope fences handle cross-XCD L2).
__global__ __launch_bounds__(NTHR) void render_combine(
        const float* __restrict__ params, float* __restrict__ partials,
        uint32* __restrict__ combineCtr, float* __restrict__ out) {
    __shared__ __align__(16) float4 gp[CHUNK * 3];
    __shared__ uint32 sOld;
    const int unit = blockIdx.x, tid = threadIdx.x;
    do_render(unit, tid, gp, params, partials);
    __syncthreads();                                  // all partials issued
    const int tile = unit >> 7, pseg = unit & 7;
    if (tid == 0) {
        __threadfence();                              // release partials
        sOld = __hip_atomic_fetch_add(&combineCtr[tile * 8 + pseg], 1u,
                                      __ATOMIC_ACQ_REL, __HIP_MEMORY_SCOPE_AGENT);
    }
    __syncthreads();
    if (sOld == NCHUNK - 1) {                         // last arriver combines
        __threadfence();                              // acquire others' partials
        const int p0 = pseg * 256 + tid;
        do_combine_px(tile, p0, partials, out);
        do_combine_px(tile, p0 + 2048, partials, out);
    }
}

// ============================ standalone fallback ===========================
__global__ __launch_bounds__(NTHR) void fb_pre(const float* means, const float* cov,
        const float* depths, u16* tmb, int N) {
    do_tmb(blockIdx.x * NTHR + threadIdx.x, gridDim.x * NTHR,
           means, cov, depths, tmb, N);
}
__global__ __launch_bounds__(NTHR) void fb_findb(const u16* tmb, int N,
        uint32* bstar, uint32* selCount, uint32* bucketBase,
        uint32* bucketFill, uint32* combineCtr) {
    __shared__ uint32 hh[NHIST];
    __shared__ uint32 part[NTHR];
    __shared__ uint32 sBM[2];
    do_findb_tile(blockIdx.x, threadIdx.x, hh, part, sBM, tmb, N,
                  bstar, selCount, bucketBase, bucketFill, combineCtr);
}
__global__ __launch_bounds__(NTHR) void fb_compact(const u16* tmb, const float* depths,
        const uint32* bstar, const uint32* bucketBase, uint32* bucketFill,
        u64* sel, int N) {
    do_compact(blockIdx.x * NTHR + threadIdx.x, gridDim.x * NTHR,
               tmb, depths, bstar, bucketBase, bucketFill, sel, N);
}
__global__ __launch_bounds__(NTHR) void fb_rank(const u64* sel, const uint32* selCount,
        const float* means, const float* cov, const float* color,
        const float* opac, float* params) {
    __shared__ __align__(16) u64 keys[SELCAP];
    do_rank(blockIdx.x, threadIdx.x, keys, sel, selCount, means, cov, color,
            opac, params);
}

// ------------------------------------------------------------------ launch --
extern "C" void kernel_launch(void* const* d_in, const int* in_sizes, int n_in,
                              void* d_out, int out_size, void* d_ws, size_t ws_size,
                              hipStream_t stream) {
    const float* means  = (const float*)d_in[0];
    const float* cov    = (const float*)d_in[1];
    const float* color  = (const float*)d_in[2];
    const float* opac   = (const float*)d_in[3];
    const float* depths = (const float*)d_in[4];
    int N = in_sizes[4];

    char* ws = (char*)d_ws;
    size_t off = 0;
    u16*    tmb        = (u16*)(ws + off);    off += ((size_t)N * 2 + 255) & ~255ull;
    uint32* bstar      = (uint32*)(ws + off); off += 256;
    uint32* selCount   = (uint32*)(ws + off); off += 256;
    uint32* bucketBase = (uint32*)(ws + off); off += (size_t)NTILES * NHIST * 4;  // 64 KB
    uint32* bucketFill = (uint32*)(ws + off); off += (size_t)NTILES * NHIST * 4;  // 64 KB
    u64*    sel        = (u64*)(ws + off);    off += (size_t)NTILES * SELCAP * 8; // 128 KB
    float*  params     = (float*)(ws + off);  off += (size_t)NTILES * PMAX * 12 * 4; // 384 KB
    uint32* combineCtr = (uint32*)(ws + off); off += 256;
    uint32* flags      = (uint32*)(ws + off); off += (size_t)NEPOCH * SBLK * FLAGSTRIDE * 4; // 12 KB
    float*  partials   = (float*)(ws + off);  off += 6 * PLANE * 4;               // 6 MB
    float*  out        = (float*)d_out;

    void* args[] = { (void*)&means, (void*)&cov, (void*)&color, (void*)&opac,
                     (void*)&depths, (void*)&N, (void*)&tmb, (void*)&bstar,
                     (void*)&selCount, (void*)&bucketBase, (void*)&bucketFill,
                     (void*)&sel, (void*)&params, (void*)&combineCtr,
                     (void*)&flags };
    hipError_t e = hipLaunchCooperativeKernel((const void*)select_k, dim3(SBLK),
                                              dim3(NTHR), args, 0, stream);
    if (e != hipSuccess) {
        (void)hipGetLastError();   // clear sticky error; proven sequential path
        fb_pre<<<(N + NTHR - 1) / NTHR, NTHR, 0, stream>>>(means, cov, depths, tmb, N);
        fb_findb<<<NTILES, NTHR, 0, stream>>>(tmb, N, bstar, selCount, bucketBase,
                                              bucketFill, combineCtr);
        fb_compact<<<(N + NTHR - 1) / NTHR, NTHR, 0, stream>>>(tmb, depths, bstar,
                                                               bucketBase, bucketFill,
                                                               sel, N);
        fb_rank<<<SBLK, NTHR, 0, stream>>>(sel, selCount, means, cov, color,
                                           opac, params);
    }
    render_combine<<<RUNITS, NTHR, 0, stream>>>(params, partials, combineCtr, out);
}

// Round 8
// 212.386 us; speedup vs baseline: 1.7981x; 1.7981x over previous
//
#include <hip/hip_runtime.h>

// Problem constants (image 128x128, TILE_SIZE=64)
#define IMG 128
#define TSZ 64
#define NTILES 4          // (128/64)^2
#define PMAX 2048
#define SELCAP 4096       // candidate cap per tile (expected ~2090)
#define NHIST 4096        // linear depth buckets (width 1/256 depth unit)
#define NCHUNK 16
#define CHUNK 128         // PMAX / NCHUNK
#define NPIX 4096         // TSZ*TSZ
#define PLANE ((size_t)NTILES * NCHUNK * NPIX)   // 262144 floats per plane
#define NTHR 256
#define SBLK 64           // select_k grid (coop co-residency trivially satisfied)
#define RUNITS 512        // render units: tile(4) x chunk(16) x pseg(8)
#define FLAGSTRIDE 16     // one cache line per flag
#define NEPOCH 4
// zero region: hist (16384 w) + bucketFill (16384 w) + combineCtr (64 w)
#define ZWORDS (NTILES * NHIST * 2 + 64)

typedef unsigned short u16;
typedef unsigned int uint32;
typedef unsigned long long u64;

// Linear depth bucketing: monotone in depth, uniform occupancy for uniform
// depths (float-bits>>20 concentrated ~56 buckets -> atomic serialization).
__device__ __forceinline__ uint32 dbucket(float d) {
    int b = (int)(d * 256.0f);
    return (uint32)min(max(b, 0), NHIST - 1);
}

__device__ __forceinline__ void gauss_rect(const float* means, const float* cov,
                                           int i, float& rminx, float& rminy,
                                           float& rmaxx, float& rmaxy) {
    const float4 cv = ((const float4*)cov)[i];           // a, b, c2, d
    float det = cv.x * cv.w - cv.y * cv.z;
    float mid = 0.5f * (cv.x + cv.w);
    float s = sqrtf(fmaxf(mid * mid - det, 0.1f));
    float radius = 3.0f * ceilf(sqrtf(fmaxf(mid + s, mid - s)));
    const float2 m = ((const float2*)means)[i];
    rminx = fminf(fmaxf(m.x - radius, 0.f), (float)(IMG - 1));
    rmaxx = fminf(fmaxf(m.x + radius, 0.f), (float)(IMG - 1));
    rminy = fminf(fmaxf(m.y - radius, 0.f), (float)(IMG - 1));
    rmaxy = fminf(fmaxf(m.y + radius, 0.f), (float)(IMG - 1));
}

__device__ __forceinline__ bool tile_overlap(int t, float rminx, float rminy,
                                             float rmaxx, float rmaxy) {
    float wmin = (float)((t & 1) * TSZ), hmin = (float)((t >> 1) * TSZ);
    float wmax = wmin + (float)(TSZ - 1), hmax = hmin + (float)(TSZ - 1);
    return (fminf(rmaxx, wmax) > fmaxf(rminx, wmin)) &&
           (fminf(rmaxy, hmax) > fmaxf(rminy, hmin));
}

// Init-free inter-block barrier for SBLK co-resident blocks. Per-epoch,
// per-block flag words (own cache line); "arrived" = magic(epoch) which can
// never equal the 0xAAAAAAAA ws poison, so no zero-init pass is needed.
// ~1-3 us vs ~55 us for cg::grid_group::sync() at 512 blocks (R6 measurement).
__device__ __forceinline__ void sbar(uint32* flags, int ep, int blk) {
    __syncthreads();
    if (threadIdx.x == 0) {
        __threadfence();                                  // release prior writes
        __hip_atomic_store(&flags[(ep * SBLK + blk) * FLAGSTRIDE],
                           0x51700000u + (uint32)ep,
                           __ATOMIC_RELEASE, __HIP_MEMORY_SCOPE_AGENT);
    }
    if (threadIdx.x < SBLK) {
        const uint32 want = 0x51700000u + (uint32)ep;
        while (__hip_atomic_load(&flags[(ep * SBLK + (int)threadIdx.x) * FLAGSTRIDE],
                                 __ATOMIC_ACQUIRE, __HIP_MEMORY_SCOPE_AGENT) != want)
            __builtin_amdgcn_s_sleep(2);
    }
    __syncthreads();
}

// ============================ phase bodies ==================================

__device__ __forceinline__ void do_zero(int gtid, int gsize, uint32* z) {
    for (int i = gtid; i < ZWORDS; i += gsize) z[i] = 0u;
}

// tmb + per-tile global hist atomics (fire-and-forget; linear buckets keep
// ~18 adds/address -> uncontended; R3/R4-proven ~3-4 us full-grid).
__device__ __forceinline__ void do_tmb_hist(int gtid, int gsize,
        const float* means, const float* cov, const float* depths,
        uint32* hist, u16* tmb, int N) {
    for (int i = gtid; i < N; i += gsize) {
        float rminx, rminy, rmaxx, rmaxy;
        gauss_rect(means, cov, i, rminx, rminy, rmaxx, rmaxy);
        uint32 b = dbucket(depths[i]);
        uint32 mask = 0;
        #pragma unroll
        for (int t = 0; t < NTILES; t++) {
            if (tile_overlap(t, rminx, rminy, rmaxx, rmaxy)) {
                mask |= (1u << t);
                atomicAdd(&hist[t * NHIST + b], 1u);      // no return -> no stall
            }
        }
        tmb[i] = (u16)((mask << 12) | b);
    }
}

// tile in [0,4): read 16 KB global hist coalesced -> LDS, scan -> b*,
// bucketBase (exclusive prefix), selCount.
__device__ __forceinline__ void do_findb_tile(int tile, int tid,
        uint32* hh, uint32* part, uint32* sBM, const uint32* hist,
        uint32* bstar, uint32* selCount, uint32* bucketBase) {
    if (tid == 0) { sBM[0] = NHIST - 1; sBM[1] = 0; }
    const uint32* h = hist + (size_t)tile * NHIST;
    for (int j = tid; j < NHIST; j += NTHR) hh[j] = h[j];   // coalesced
    __syncthreads();
    uint32 local = 0;
    #pragma unroll
    for (int b = 0; b < 16; b++) local += hh[tid * 16 + b];
    part[tid] = local;
    __syncthreads();
    for (int off = 1; off < NTHR; off <<= 1) {
        uint32 v = part[tid];
        uint32 u = (tid >= off) ? part[tid - off] : 0u;
        __syncthreads();
        part[tid] = v + u;
        __syncthreads();
    }
    uint32 incl = part[tid], excl = incl - local;
    uint32 run = excl;
    #pragma unroll
    for (int b = 0; b < 16; b++) {
        uint32 j = (uint32)(tid * 16 + b);
        bucketBase[(size_t)tile * NHIST + j] = run;
        run += hh[j];
    }
    if (excl < PMAX && incl >= PMAX) {                    // unique crossing thread
        uint32 cum = excl;
        for (int b = 0; b < 16; b++) {
            cum += hh[tid * 16 + b];
            if (cum >= PMAX) { sBM[0] = (uint32)(tid * 16 + b); sBM[1] = cum; break; }
        }
    }
    __syncthreads();
    if (tid == 0) {
        bstar[tile] = sBM[0];
        selCount[tile] = (sBM[1] != 0) ? sBM[1] : part[NTHR - 1];
    }
}

__device__ __forceinline__ void do_compact(int gtid, int gsize,
        const u16* tmb, const float* depths, const uint32* bstar,
        const uint32* bucketBase, uint32* bucketFill, u64* sel, int N) {
    for (int i = gtid; i < N; i += gsize) {
        uint32 tm = tmb[i];
        uint32 mask = tm >> 12;
        if (!mask) continue;
        uint32 b = tm & 0xFFFu;
        u64 key = ((u64)__float_as_uint(depths[i]) << 32) | (uint32)i;
        #pragma unroll
        for (int t = 0; t < NTILES; t++) {
            if (((mask >> t) & 1u) && b <= bstar[t]) {
                uint32 pos = bucketBase[(size_t)t * NHIST + b]
                           + atomicAdd(&bucketFill[(size_t)t * NHIST + b], 1u);
                if (pos < SELCAP) sel[(size_t)t * SELCAP + pos] = key;
            }
        }
    }
}

// unit in [0,64): exact rank = #{j: key_j < key_i} (keys unique) = sorted
// slot; emit render-param record. Slots in [M,PMAX) get explicit zero pads.
__device__ __forceinline__ void do_rank(int unit, int tid, u64* keys,
        const u64* sel, const uint32* selCount,
        const float* means, const float* cov,
        const float* color, const float* opac, float* params) {
    const int tile = unit >> 4;
    uint32 M = selCount[tile]; if (M > SELCAP) M = SELCAP;
    uint32 Mp = (M + 7u) & ~7u;
    const u64* s = sel + (size_t)tile * SELCAP;
    for (uint32 j = tid; j < Mp; j += NTHR)
        keys[j] = (j < M) ? s[j] : ~0ULL;
    __syncthreads();
    uint32 i = (uint32)(unit & 15) * NTHR + (uint32)tid;
    if (i < M) {
        u64 ki = keys[i];
        uint32 r = 0;
        const ulonglong2* k2 = (const ulonglong2*)keys;
        uint32 n2 = Mp >> 1;
        #pragma unroll 8
        for (uint32 j = 0; j < n2; j++) {
            ulonglong2 kk = k2[j];                        // LDS broadcast (16B)
            r += (kk.x < ki) ? 1u : 0u;
            r += (kk.y < ki) ? 1u : 0u;
        }
        if (r < PMAX) {
            uint32 idx = (uint32)(ki & 0xffffffffu);
            float a = cov[4*idx], b = cov[4*idx+1], c2 = cov[4*idx+2], d = cov[4*idx+3];
            float invdet = 1.0f / fmaxf(a * d - b * c2, 1e-6f);
            float4 p0, p1, p2;
            p0.x = means[2*idx]; p0.y = means[2*idx+1];
            p0.z = d * invdet;                 // c00
            p0.w = -(b + c2) * invdet;         // c01 + c10
            p1.x = a * invdet;                 // c11
            p1.y = opac[idx];
            p1.z = color[3*idx]; p1.w = color[3*idx+1];
            p2.x = color[3*idx+2];
            p2.y = __uint_as_float((uint32)(ki >> 32));   // depth
            p2.z = 0.f; p2.w = 0.f;
            float4* P = (float4*)(params + ((size_t)tile * PMAX + r) * 12);
            P[0] = p0; P[1] = p1; P[2] = p2;
        }
    } else if (i < PMAX) {                                // zero-pad slot i
        float4 z = {0.f, 0.f, 0.f, 0.f};
        float4* P = (float4*)(params + ((size_t)tile * PMAX + i) * 12);
        P[0] = z; P[1] = z; P[2] = z;
    }
}

// unit in [0,512): 2 px/thread (rows y, y+32 share all LDS reads).
__device__ __forceinline__ void do_render(int unit, int tid, float4* gp,
        const float* params, float* partials) {
    const int tile  = unit >> 7;
    const int chunk = (unit >> 3) & 15;
    const int pseg  = unit & 7;
    const float4* src = (const float4*)(params + ((size_t)tile * PMAX + (size_t)chunk * CHUNK) * 12);
    for (int j = tid; j < CHUNK * 3; j += NTHR) gp[j] = src[j];
    __syncthreads();
    const int p0 = pseg * 256 + tid;               // rows pseg*4 .. pseg*4+3
    float px  = (float)((tile & 1) * TSZ + (p0 & 63));
    float py0 = (float)((tile >> 1) * TSZ + (p0 >> 6));
    float py1 = py0 + 32.0f;
    float T0 = 1.f, cr0 = 0.f, cg0 = 0.f, cb0 = 0.f, dp0 = 0.f, ac0 = 0.f;
    float T1 = 1.f, cr1 = 0.f, cg1 = 0.f, cb1 = 0.f, dp1 = 0.f, ac1 = 0.f;
    #pragma unroll 4
    for (int g = 0; g < CHUNK; g++) {
        float4 q0 = gp[3*g], q1 = gp[3*g+1], q2 = gp[3*g+2];
        float dx   = px - q0.x;
        float dx2c = dx * dx * q0.z;
        float dxw  = dx * q0.w;
        float dy, power, al, w;
        dy = py0 - q0.y;
        power = -0.5f * (dx2c + dy * dy * q1.x + dy * dxw);
        al = fminf(__expf(power) * q1.y, 0.99f);
        w = al * T0;
        cr0 += w * q1.z; cg0 += w * q1.w; cb0 += w * q2.x;
        dp0 += w * q2.y; ac0 += w;
        T0 *= (1.f - al);
        dy = py1 - q0.y;
        power = -0.5f * (dx2c + dy * dy * q1.x + dy * dxw);
        al = fminf(__expf(power) * q1.y, 0.99f);
        w = al * T1;
        cr1 += w * q1.z; cg1 += w * q1.w; cb1 += w * q2.x;
        dp1 += w * q2.y; ac1 += w;
        T1 *= (1.f - al);
    }
    size_t base0 = ((size_t)tile * NCHUNK + chunk) * NPIX + (size_t)p0;
    size_t base1 = base0 + 2048;                   // row +32
    partials[0*PLANE + base0] = T0;  partials[0*PLANE + base1] = T1;
    partials[1*PLANE + base0] = cr0; partials[1*PLANE + base1] = cr1;
    partials[2*PLANE + base0] = cg0; partials[2*PLANE + base1] = cg1;
    partials[3*PLANE + base0] = cb0; partials[3*PLANE + base1] = cb1;
    partials[4*PLANE + base0] = dp0; partials[4*PLANE + base1] = dp1;
    partials[5*PLANE + base0] = ac0; partials[5*PLANE + base1] = ac1;
}

// fold chunks for one pixel via (T1*T2, S1 + T1*S2); write final output.
__device__ __forceinline__ void do_combine_px(int tile, int p,
        const float* partials, float* out) {
    float T = 1.f, cr = 0.f, cg = 0.f, cb = 0.f, dep = 0.f, acc = 0.f;
    #pragma unroll
    for (int c = 0; c < NCHUNK; c++) {
        size_t base = ((size_t)tile * NCHUNK + c) * NPIX + (size_t)p;
        float Tk = partials[0*PLANE + base];
        cr  += T * partials[1*PLANE + base];
        cg  += T * partials[2*PLANE + base];
        cb  += T * partials[3*PLANE + base];
        dep += T * partials[4*PLANE + base];
        acc += T * partials[5*PLANE + base];
        T *= Tk;
    }
    int gx = (tile & 1) * TSZ + (p & 63);
    int gy = (tile >> 1) * TSZ + (p >> 6);
    int pix = gy * IMG + gx;
    float wb = 1.f - acc;                           // WHITE_BKGD
    out[3*pix+0] = cr + wb;
    out[3*pix+1] = cg + wb;
    out[3*pix+2] = cb + wb;
    out[IMG*IMG*3 + pix] = dep;
    out[IMG*IMG*4 + pix] = acc;
}

// ============================ kernel 1: select ==============================
// Cooperative (co-residency guarantee only; sync via init-free flag barrier).
// Phase parallelism restored to R4 assignments: hist built by FULL grid
// atomics (uncontended), findb only reads 16 KB coalesced (R7's 4-block
// 100k-item scan was 390 serialized cross-XCD loads = the 250 us).
__global__ __launch_bounds__(NTHR, 2) void select_k(
        const float* __restrict__ means, const float* __restrict__ cov,
        const float* __restrict__ color, const float* __restrict__ opac,
        const float* __restrict__ depths, int N,
        u16* __restrict__ tmb, uint32* __restrict__ bstar,
        uint32* __restrict__ selCount, uint32* __restrict__ bucketBase,
        uint32* __restrict__ zbase, u64* __restrict__ sel,
        float* __restrict__ params, uint32* __restrict__ flags) {
    const int blk = blockIdx.x, tid = threadIdx.x;
    const int gtid = blk * NTHR + tid, gsize = gridDim.x * NTHR;
    __shared__ __align__(16) char shraw[SELCAP * 8];   // 32 KB, phase-aliased
    __shared__ uint32 part[NTHR];
    __shared__ uint32 sBM[2];
    uint32* hist       = zbase;                        // [NTILES*NHIST]
    uint32* bucketFill = zbase + NTILES * NHIST;       // [NTILES*NHIST]

    do_zero(gtid, gsize, zbase);                       // hist+fill+combineCtr
    sbar(flags, 0, blk);
    do_tmb_hist(gtid, gsize, means, cov, depths, hist, tmb, N);
    sbar(flags, 1, blk);
    if (blk < NTILES)
        do_findb_tile(blk, tid, (uint32*)shraw, part, sBM, hist,
                      bstar, selCount, bucketBase);
    sbar(flags, 2, blk);
    do_compact(gtid, gsize, tmb, depths, bstar, bucketBase, bucketFill, sel, N);
    sbar(flags, 3, blk);
    do_rank(blk, tid, (u64*)shraw, sel, selCount, means, cov, color, opac, params);
}

// ============================ kernel 2: render+combine ======================
// Plain launch, 512 blocks. Last-arriver block per (tile,pseg) folds the 16
// chunk partials (device-scope fetch_add + threadfence; deadlock-free).
__global__ __launch_bounds__(NTHR) void render_combine(
        const float* __restrict__ params, float* __restrict__ partials,
        uint32* __restrict__ combineCtr, float* __restrict__ out) {
    __shared__ __align__(16) float4 gp[CHUNK * 3];
    __shared__ uint32 sOld;
    const int unit = blockIdx.x, tid = threadIdx.x;
    do_render(unit, tid, gp, params, partials);
    __syncthreads();                                  // all partials issued
    const int tile = unit >> 7, pseg = unit & 7;
    if (tid == 0) {
        __threadfence();                              // release partials
        sOld = __hip_atomic_fetch_add(&combineCtr[tile * 8 + pseg], 1u,
                                      __ATOMIC_ACQ_REL, __HIP_MEMORY_SCOPE_AGENT);
    }
    __syncthreads();
    if (sOld == NCHUNK - 1) {                         // last arriver combines
        __threadfence();                              // acquire others' partials
        const int p0 = pseg * 256 + tid;
        do_combine_px(tile, p0, partials, out);
        do_combine_px(tile, p0 + 2048, partials, out);
    }
}

// ============================ standalone fallback ===========================
__global__ __launch_bounds__(NTHR) void fb_zero(uint32* z) {
    do_zero(blockIdx.x * NTHR + threadIdx.x, gridDim.x * NTHR, z);
}
__global__ __launch_bounds__(NTHR) void fb_pre(const float* means, const float* cov,
        const float* depths, uint32* hist, u16* tmb, int N) {
    do_tmb_hist(blockIdx.x * NTHR + threadIdx.x, gridDim.x * NTHR,
                means, cov, depths, hist, tmb, N);
}
__global__ __launch_bounds__(NTHR) void fb_findb(const uint32* hist,
        uint32* bstar, uint32* selCount, uint32* bucketBase) {
    __shared__ uint32 hh[NHIST];
    __shared__ uint32 part[NTHR];
    __shared__ uint32 sBM[2];
    do_findb_tile(blockIdx.x, threadIdx.x, hh, part, sBM, hist,
                  bstar, selCount, bucketBase);
}
__global__ __launch_bounds__(NTHR) void fb_compact(const u16* tmb, const float* depths,
        const uint32* bstar, const uint32* bucketBase, uint32* bucketFill,
        u64* sel, int N) {
    do_compact(blockIdx.x * NTHR + threadIdx.x, gridDim.x * NTHR,
               tmb, depths, bstar, bucketBase, bucketFill, sel, N);
}
__global__ __launch_bounds__(NTHR) void fb_rank(const u64* sel, const uint32* selCount,
        const float* means, const float* cov, const float* color,
        const float* opac, float* params) {
    __shared__ __align__(16) u64 keys[SELCAP];
    do_rank(blockIdx.x, threadIdx.x, keys, sel, selCount, means, cov, color,
            opac, params);
}

// ------------------------------------------------------------------ launch --
extern "C" void kernel_launch(void* const* d_in, const int* in_sizes, int n_in,
                              void* d_out, int out_size, void* d_ws, size_t ws_size,
                              hipStream_t stream) {
    const float* means  = (const float*)d_in[0];
    const float* cov    = (const float*)d_in[1];
    const float* color  = (const float*)d_in[2];
    const float* opac   = (const float*)d_in[3];
    const float* depths = (const float*)d_in[4];
    int N = in_sizes[4];

    char* ws = (char*)d_ws;
    size_t off = 0;
    u16*    tmb        = (u16*)(ws + off);    off += ((size_t)N * 2 + 255) & ~255ull;
    uint32* bstar      = (uint32*)(ws + off); off += 256;
    uint32* selCount   = (uint32*)(ws + off); off += 256;
    uint32* bucketBase = (uint32*)(ws + off); off += (size_t)NTILES * NHIST * 4;  // 64 KB
    // zeroed-in-kernel region: hist | bucketFill | combineCtr (contiguous)
    uint32* zbase      = (uint32*)(ws + off); off += (size_t)ZWORDS * 4;
    uint32* hist       = zbase;
    uint32* bucketFill = zbase + NTILES * NHIST;
    uint32* combineCtr = zbase + NTILES * NHIST * 2;
    u64*    sel        = (u64*)(ws + off);    off += (size_t)NTILES * SELCAP * 8; // 128 KB
    float*  params     = (float*)(ws + off);  off += (size_t)NTILES * PMAX * 12 * 4; // 384 KB
    uint32* flags      = (uint32*)(ws + off); off += (size_t)NEPOCH * SBLK * FLAGSTRIDE * 4; // 16 KB
    float*  partials   = (float*)(ws + off);  off += 6 * PLANE * 4;               // 6 MB
    float*  out        = (float*)d_out;

    void* args[] = { (void*)&means, (void*)&cov, (void*)&color, (void*)&opac,
                     (void*)&depths, (void*)&N, (void*)&tmb, (void*)&bstar,
                     (void*)&selCount, (void*)&bucketBase, (void*)&zbase,
                     (void*)&sel, (void*)&params, (void*)&flags };
    hipError_t e = hipLaunchCooperativeKernel((const void*)select_k, dim3(SBLK),
                                              dim3(NTHR), args, 0, stream);
    if (e != hipSuccess) {
        (void)hipGetLastError();   // clear sticky error; proven sequential path
        fb_zero<<<(ZWORDS + NTHR - 1) / NTHR, NTHR, 0, stream>>>(zbase);
        fb_pre<<<(N + NTHR - 1) / NTHR, NTHR, 0, stream>>>(means, cov, depths,
                                                           hist, tmb, N);
        fb_findb<<<NTILES, NTHR, 0, stream>>>(hist, bstar, selCount, bucketBase);
        fb_compact<<<(N + NTHR - 1) / NTHR, NTHR, 0, stream>>>(tmb, depths, bstar,
                                                               bucketBase, bucketFill,
                                                               sel, N);
        fb_rank<<<SBLK, NTHR, 0, stream>>>(sel, selCount, means, cov, color,
                                           opac, params);
    }
    render_combine<<<RUNITS, NTHR, 0, stream>>>(params, partials, combineCtr, out);
}

// Round 9
// 141.621 us; speedup vs baseline: 2.6965x; 1.4997x over previous
//
#include <hip/hip_runtime.h>

// Problem constants (image 128x128, TILE_SIZE=64)
#define IMG 128
#define TSZ 64
#define NTILES 4          // (128/64)^2
#define PMAX 2048
#define SELCAP 4096       // candidate cap per tile (expected ~2090)
#define NHIST 4096        // linear depth buckets (width 1/256 depth unit)
#define NCHUNK 16
#define CHUNK 128         // PMAX / NCHUNK
#define NPIX 4096         // TSZ*TSZ
#define PLANE ((size_t)NTILES * NCHUNK * NPIX)   // 262144 floats per plane
#define NTHR 256
#define RUNITS 512        // render units: tile(4) x chunk(16) x pseg(8)
// zero region: hist (16384 w) + bucketFill (16384 w) + combineCtr (64 w)
#define ZWORDS (NTILES * NHIST * 2 + 64)

typedef unsigned short u16;
typedef unsigned int uint32;
typedef unsigned long long u64;

// Linear depth bucketing: monotone in depth, uniform occupancy for uniform
// depths (float-bits>>20 concentrated ~56 buckets -> atomic serialization).
__device__ __forceinline__ uint32 dbucket(float d) {
    int b = (int)(d * 256.0f);
    return (uint32)min(max(b, 0), NHIST - 1);
}

__device__ __forceinline__ void gauss_rect(const float* means, const float* cov,
                                           int i, float& rminx, float& rminy,
                                           float& rmaxx, float& rmaxy) {
    const float4 cv = ((const float4*)cov)[i];           // a, b, c2, d
    float det = cv.x * cv.w - cv.y * cv.z;
    float mid = 0.5f * (cv.x + cv.w);
    float s = sqrtf(fmaxf(mid * mid - det, 0.1f));
    float radius = 3.0f * ceilf(sqrtf(fmaxf(mid + s, mid - s)));
    const float2 m = ((const float2*)means)[i];
    rminx = fminf(fmaxf(m.x - radius, 0.f), (float)(IMG - 1));
    rmaxx = fminf(fmaxf(m.x + radius, 0.f), (float)(IMG - 1));
    rminy = fminf(fmaxf(m.y - radius, 0.f), (float)(IMG - 1));
    rmaxy = fminf(fmaxf(m.y + radius, 0.f), (float)(IMG - 1));
}

__device__ __forceinline__ bool tile_overlap(int t, float rminx, float rminy,
                                             float rmaxx, float rmaxy) {
    float wmin = (float)((t & 1) * TSZ), hmin = (float)((t >> 1) * TSZ);
    float wmax = wmin + (float)(TSZ - 1), hmax = hmin + (float)(TSZ - 1);
    return (fminf(rmaxx, wmax) > fmaxf(rminx, wmin)) &&
           (fminf(rmaxy, hmax) > fmaxf(rminy, hmin));
}

// ---------------------------------------------------------------- zero ------
__global__ __launch_bounds__(NTHR) void k_zero(uint32* __restrict__ z) {
    int i = blockIdx.x * NTHR + threadIdx.x;
    if (i < ZWORDS) z[i] = 0u;
}

// -------------------------------------------------- tmb + per-tile histogram
// Full grid; fire-and-forget atomics spread over ~2600 buckets (uncontended).
__global__ __launch_bounds__(NTHR) void k_pre(
        const float* __restrict__ means, const float* __restrict__ cov,
        const float* __restrict__ depths, uint32* __restrict__ hist,
        u16* __restrict__ tmb, int N) {
    int i = blockIdx.x * NTHR + threadIdx.x;
    if (i >= N) return;
    float rminx, rminy, rmaxx, rmaxy;
    gauss_rect(means, cov, i, rminx, rminy, rmaxx, rmaxy);
    uint32 b = dbucket(depths[i]);
    uint32 mask = 0;
    #pragma unroll
    for (int t = 0; t < NTILES; t++) {
        if (tile_overlap(t, rminx, rminy, rmaxx, rmaxy)) {
            mask |= (1u << t);
            atomicAdd(&hist[t * NHIST + b], 1u);          // no return -> no stall
        }
    }
    tmb[i] = (u16)((mask << 12) | b);
}

// ------------------------------------------------------------------- findb --
// One block per tile: 16 KB coalesced hist read -> LDS scan -> b*,
// exclusive bucketBase prefix, exact selCount.
__global__ __launch_bounds__(NTHR) void k_findb(const uint32* __restrict__ hist,
        uint32* __restrict__ bstar, uint32* __restrict__ selCount,
        uint32* __restrict__ bucketBase) {
    int tile = blockIdx.x, tid = threadIdx.x;
    __shared__ uint32 hh[NHIST];
    __shared__ uint32 part[NTHR];
    __shared__ uint32 sBM[2];
    if (tid == 0) { sBM[0] = NHIST - 1; sBM[1] = 0; }
    const uint32* h = hist + (size_t)tile * NHIST;
    for (int j = tid; j < NHIST; j += NTHR) hh[j] = h[j];   // coalesced
    __syncthreads();
    uint32 local = 0;
    #pragma unroll
    for (int b = 0; b < 16; b++) local += hh[tid * 16 + b];
    part[tid] = local;
    __syncthreads();
    for (int off = 1; off < NTHR; off <<= 1) {
        uint32 v = part[tid];
        uint32 u = (tid >= off) ? part[tid - off] : 0u;
        __syncthreads();
        part[tid] = v + u;
        __syncthreads();
    }
    uint32 incl = part[tid], excl = incl - local;
    uint32 run = excl;
    #pragma unroll
    for (int b = 0; b < 16; b++) {
        uint32 j = (uint32)(tid * 16 + b);
        bucketBase[(size_t)tile * NHIST + j] = run;
        run += hh[j];
    }
    if (excl < PMAX && incl >= PMAX) {                    // unique crossing thread
        uint32 cum = excl;
        for (int b = 0; b < 16; b++) {
            cum += hh[tid * 16 + b];
            if (cum >= PMAX) { sBM[0] = (uint32)(tid * 16 + b); sBM[1] = cum; break; }
        }
    }
    __syncthreads();
    if (tid == 0) {
        bstar[tile] = sBM[0];
        selCount[tile] = (sBM[1] != 0) ? sBM[1] : part[NTHR - 1];
    }
}

// ----------------------------------------------------------------- compact --
// Deterministic bucket-scatter: pos = bucketBase[b] + fill. ~4 atomics per
// populated bucket -> uncontended (vs single-counter serialization, R3).
__global__ __launch_bounds__(NTHR) void k_compact(const u16* __restrict__ tmb,
        const float* __restrict__ depths, const uint32* __restrict__ bstar,
        const uint32* __restrict__ bucketBase, uint32* __restrict__ bucketFill,
        u64* __restrict__ sel, int N) {
    int i = blockIdx.x * NTHR + threadIdx.x;
    if (i >= N) return;
    uint32 tm = tmb[i];
    uint32 mask = tm >> 12;
    if (!mask) return;
    uint32 b = tm & 0xFFFu;
    u64 key = ((u64)__float_as_uint(depths[i]) << 32) | (uint32)i;
    #pragma unroll
    for (int t = 0; t < NTILES; t++) {
        if (((mask >> t) & 1u) && b <= bstar[t]) {
            uint32 pos = bucketBase[(size_t)t * NHIST + b]
                       + atomicAdd(&bucketFill[(size_t)t * NHIST + b], 1u);
            if (pos < SELCAP) sel[(size_t)t * SELCAP + pos] = key;
        }
    }
}

// ------------------------------------------------------------ bucket rank --
// Global rank of candidate = bucketBase[b] (global rank of its bucket's
// start; buckets < b are fully selected since b <= b*) + local rank among
// the ~18 same-bucket candidates (contiguous span in sel). Replaces the
// all-pairs scan over ~2100 keys with ~20 L1-resident 8B loads.
__global__ __launch_bounds__(NTHR) void k_rank(const u64* __restrict__ sel,
        const uint32* __restrict__ selCount, const uint32* __restrict__ bucketBase,
        const uint32* __restrict__ bucketFill,
        const float* __restrict__ means, const float* __restrict__ cov,
        const float* __restrict__ color, const float* __restrict__ opac,
        float* __restrict__ params) {
    const int tile = blockIdx.x >> 4;
    uint32 p = (uint32)(blockIdx.x & 15) * NTHR + (uint32)threadIdx.x;  // 0..4095
    uint32 M = selCount[tile]; if (M > SELCAP) M = SELCAP;
    const u64* s = sel + (size_t)tile * SELCAP;
    if (p < M) {
        u64 ki = s[p];
        float d = __uint_as_float((uint32)(ki >> 32));
        uint32 b = dbucket(d);
        uint32 s0  = bucketBase[(size_t)tile * NHIST + b];
        uint32 cnt = bucketFill[(size_t)tile * NHIST + b];
        uint32 end = s0 + cnt; if (end > SELCAP) end = SELCAP;
        uint32 r = s0;
        for (uint32 j = s0; j < end; j++)
            r += (s[j] < ki) ? 1u : 0u;                   // keys unique
        if (r < PMAX) {
            uint32 idx = (uint32)(ki & 0xffffffffu);
            float a = cov[4*idx], bb = cov[4*idx+1], c2 = cov[4*idx+2], dd = cov[4*idx+3];
            float invdet = 1.0f / fmaxf(a * dd - bb * c2, 1e-6f);
            float4 p0, p1, p2;
            p0.x = means[2*idx]; p0.y = means[2*idx+1];
            p0.z = dd * invdet;                // c00
            p0.w = -(bb + c2) * invdet;        // c01 + c10
            p1.x = a * invdet;                 // c11
            p1.y = opac[idx];
            p1.z = color[3*idx]; p1.w = color[3*idx+1];
            p2.x = color[3*idx+2];
            p2.y = d;                          // depth
            p2.z = 0.f; p2.w = 0.f;
            float4* P = (float4*)(params + ((size_t)tile * PMAX + r) * 12);
            P[0] = p0; P[1] = p1; P[2] = p2;
        }
    } else if (p < PMAX) {                                // zero-pad slot p
        float4 z = {0.f, 0.f, 0.f, 0.f};
        float4* P = (float4*)(params + ((size_t)tile * PMAX + p) * 12);
        P[0] = z; P[1] = z; P[2] = z;
    }
}

// ------------------------------------------------------- render + combine --
// 512 blocks: unit = tile(4) x chunk(16) x pseg(8); 2 px/thread (rows y and
// y+32 share all LDS reads). Last-arriver block per (tile,pseg) folds the 16
// chunk partials via (T1*T2, S1 + T1*S2) — R7/R8-validated pattern.
__global__ __launch_bounds__(NTHR) void k_render_combine(
        const float* __restrict__ params, float* __restrict__ partials,
        uint32* __restrict__ combineCtr, float* __restrict__ out) {
    __shared__ __align__(16) float4 gp[CHUNK * 3];
    __shared__ uint32 sOld;
    const int unit = blockIdx.x, tid = threadIdx.x;
    const int tile  = unit >> 7;
    const int chunk = (unit >> 3) & 15;
    const int pseg  = unit & 7;
    const float4* src = (const float4*)(params + ((size_t)tile * PMAX + (size_t)chunk * CHUNK) * 12);
    for (int j = tid; j < CHUNK * 3; j += NTHR) gp[j] = src[j];
    __syncthreads();
    const int p0 = pseg * 256 + tid;               // rows pseg*4 .. pseg*4+3
    float px  = (float)((tile & 1) * TSZ + (p0 & 63));
    float py0 = (float)((tile >> 1) * TSZ + (p0 >> 6));
    float py1 = py0 + 32.0f;
    float T0 = 1.f, cr0 = 0.f, cg0 = 0.f, cb0 = 0.f, dp0 = 0.f, ac0 = 0.f;
    float T1 = 1.f, cr1 = 0.f, cg1 = 0.f, cb1 = 0.f, dp1 = 0.f, ac1 = 0.f;
    #pragma unroll 4
    for (int g = 0; g < CHUNK; g++) {
        float4 q0 = gp[3*g], q1 = gp[3*g+1], q2 = gp[3*g+2];
        float dx   = px - q0.x;
        float dx2c = dx * dx * q0.z;
        float dxw  = dx * q0.w;
        float dy, power, al, w;
        dy = py0 - q0.y;
        power = -0.5f * (dx2c + dy * dy * q1.x + dy * dxw);
        al = fminf(__expf(power) * q1.y, 0.99f);
        w = al * T0;
        cr0 += w * q1.z; cg0 += w * q1.w; cb0 += w * q2.x;
        dp0 += w * q2.y; ac0 += w;
        T0 *= (1.f - al);
        dy = py1 - q0.y;
        power = -0.5f * (dx2c + dy * dy * q1.x + dy * dxw);
        al = fminf(__expf(power) * q1.y, 0.99f);
        w = al * T1;
        cr1 += w * q1.z; cg1 += w * q1.w; cb1 += w * q2.x;
        dp1 += w * q2.y; ac1 += w;
        T1 *= (1.f - al);
    }
    size_t base0 = ((size_t)tile * NCHUNK + chunk) * NPIX + (size_t)p0;
    size_t base1 = base0 + 2048;                   // row +32
    partials[0*PLANE + base0] = T0;  partials[0*PLANE + base1] = T1;
    partials[1*PLANE + base0] = cr0; partials[1*PLANE + base1] = cr1;
    partials[2*PLANE + base0] = cg0; partials[2*PLANE + base1] = cg1;
    partials[3*PLANE + base0] = cb0; partials[3*PLANE + base1] = cb1;
    partials[4*PLANE + base0] = dp0; partials[4*PLANE + base1] = dp1;
    partials[5*PLANE + base0] = ac0; partials[5*PLANE + base1] = ac1;
    __syncthreads();                                  // all partials issued
    if (tid == 0) {
        __threadfence();                              // release partials
        sOld = __hip_atomic_fetch_add(&combineCtr[tile * 8 + pseg], 1u,
                                      __ATOMIC_ACQ_REL, __HIP_MEMORY_SCOPE_AGENT);
    }
    __syncthreads();
    if (sOld == NCHUNK - 1) {                         // last arriver combines
        __threadfence();                              // acquire others' partials
        #pragma unroll
        for (int half = 0; half < 2; half++) {
            int p = p0 + half * 2048;
            float T = 1.f, cr = 0.f, cg = 0.f, cb = 0.f, dep = 0.f, acc = 0.f;
            #pragma unroll
            for (int c = 0; c < NCHUNK; c++) {
                size_t base = ((size_t)tile * NCHUNK + c) * NPIX + (size_t)p;
                float Tk = partials[0*PLANE + base];
                cr  += T * partials[1*PLANE + base];
                cg  += T * partials[2*PLANE + base];
                cb  += T * partials[3*PLANE + base];
                dep += T * partials[4*PLANE + base];
                acc += T * partials[5*PLANE + base];
                T *= Tk;
            }
            int gx = (tile & 1) * TSZ + (p & 63);
            int gy = (tile >> 1) * TSZ + (p >> 6);
            int pix = gy * IMG + gx;
            float wb = 1.f - acc;                     // WHITE_BKGD
            out[3*pix+0] = cr + wb;
            out[3*pix+1] = cg + wb;
            out[3*pix+2] = cb + wb;
            out[IMG*IMG*3 + pix] = dep;
            out[IMG*IMG*4 + pix] = acc;
        }
    }
}

// ------------------------------------------------------------------ launch --
extern "C" void kernel_launch(void* const* d_in, const int* in_sizes, int n_in,
                              void* d_out, int out_size, void* d_ws, size_t ws_size,
                              hipStream_t stream) {
    const float* means  = (const float*)d_in[0];
    const float* cov    = (const float*)d_in[1];
    const float* color  = (const float*)d_in[2];
    const float* opac   = (const float*)d_in[3];
    const float* depths = (const float*)d_in[4];
    int N = in_sizes[4];

    char* ws = (char*)d_ws;
    size_t off = 0;
    u16*    tmb        = (u16*)(ws + off);    off += ((size_t)N * 2 + 255) & ~255ull;
    uint32* bstar      = (uint32*)(ws + off); off += 256;
    uint32* selCount   = (uint32*)(ws + off); off += 256;
    uint32* bucketBase = (uint32*)(ws + off); off += (size_t)NTILES * NHIST * 4;  // 64 KB
    // zeroed region: hist | bucketFill | combineCtr (contiguous)
    uint32* zbase      = (uint32*)(ws + off); off += (size_t)ZWORDS * 4;
    uint32* hist       = zbase;
    uint32* bucketFill = zbase + NTILES * NHIST;
    uint32* combineCtr = zbase + NTILES * NHIST * 2;
    u64*    sel        = (u64*)(ws + off);    off += (size_t)NTILES * SELCAP * 8; // 128 KB
    float*  params     = (float*)(ws + off);  off += (size_t)NTILES * PMAX * 12 * 4; // 384 KB
    float*  partials   = (float*)(ws + off);  off += 6 * PLANE * 4;               // 6 MB
    float*  out        = (float*)d_out;

    k_zero<<<(ZWORDS + NTHR - 1) / NTHR, NTHR, 0, stream>>>(zbase);
    k_pre<<<(N + NTHR - 1) / NTHR, NTHR, 0, stream>>>(means, cov, depths,
                                                      hist, tmb, N);
    k_findb<<<NTILES, NTHR, 0, stream>>>(hist, bstar, selCount, bucketBase);
    k_compact<<<(N + NTHR - 1) / NTHR, NTHR, 0, stream>>>(tmb, depths, bstar,
                                                          bucketBase, bucketFill,
                                                          sel, N);
    k_rank<<<NTILES * (SELCAP / NTHR), NTHR, 0, stream>>>(sel, selCount,
                                                          bucketBase, bucketFill,
                                                          means, cov, color,
                                                          opac, params);
    k_render_combine<<<RUNITS, NTHR, 0, stream>>>(params, partials, combineCtr, out);
}